// Round 5
// baseline (580.553 us; speedup 1.0000x reference)
//
#include <hip/hip_runtime.h>
#include <hip/hip_bf16.h>
#include <hip/hip_fp16.h>

#define N_NODES 50000
#define N_EDGES 800000
#define E_TOT   850000   // + self loops
#define SCAN_BLOCKS 196  // ceil(50000/256)
#define GBLK 64          // nodes per gemm block
#define GEMM_BLOCKS 782  // ceil(50000/64)
#define SCAT_BLOCKS 3321 // ceil(850000/256)

// ---------------- CSR build ----------------

__global__ void hist_kernel(const int* __restrict__ ei, int* __restrict__ counts) {
    int e = blockIdx.x * blockDim.x + threadIdx.x;
    if (e >= E_TOT) return;
    int d = (e < N_EDGES) ? ei[N_EDGES + e] : (e - N_EDGES);
    atomicAdd(&counts[d], 1);
}

// hierarchical exclusive scan: local 256-scan -> block-sum scan -> add base
__global__ __launch_bounds__(256) void scan1_kernel(const int* __restrict__ counts,
                                                    int* __restrict__ localScan,
                                                    int* __restrict__ blockSums) {
    __shared__ int tmp[256];
    int t = threadIdx.x, i = blockIdx.x * 256 + t;
    int v = (i < N_NODES) ? counts[i] : 0;
    tmp[t] = v;
    __syncthreads();
    for (int d = 1; d < 256; d <<= 1) {
        int u = (t >= d) ? tmp[t - d] : 0;
        __syncthreads();
        tmp[t] += u;
        __syncthreads();
    }
    if (i < N_NODES) localScan[i] = tmp[t] - v;  // exclusive
    if (t == 255) blockSums[blockIdx.x] = tmp[t];
}

__global__ __launch_bounds__(256) void scan2_kernel(const int* __restrict__ blockSums,
                                                    int* __restrict__ blockBase) {
    __shared__ int tmp[256];
    int t = threadIdx.x;
    int v = (t < SCAN_BLOCKS) ? blockSums[t] : 0;
    tmp[t] = v;
    __syncthreads();
    for (int d = 1; d < 256; d <<= 1) {
        int u = (t >= d) ? tmp[t - d] : 0;
        __syncthreads();
        tmp[t] += u;
        __syncthreads();
    }
    blockBase[t] = tmp[t] - v;  // exclusive
}

__global__ void scan3_kernel(const int* __restrict__ localScan,
                             const int* __restrict__ blockBase,
                             int* __restrict__ offs, int* __restrict__ fill) {
    int i = blockIdx.x * 256 + threadIdx.x;
    if (i < N_NODES) {
        int o = localScan[i] + blockBase[i >> 8];
        offs[i] = o;
        fill[i] = o;
    }
    if (i == 0) offs[N_NODES] = E_TOT;
}

// deterministic ordering: sort each node's bucket by src id.
// one WAVE per node; <=64 elements sorted in-register via bitonic network.
__global__ __launch_bounds__(256) void sort_kernel(const int* __restrict__ offs,
                                                   int* __restrict__ bucket) {
    int w = (blockIdx.x * blockDim.x + threadIdx.x) >> 6;
    int l = threadIdx.x & 63;
    if (w >= N_NODES) return;
    int a = offs[w];
    int deg = offs[w + 1] - a;
    if (deg <= 1) return;
    if (deg <= 64) {
        int v = (l < deg) ? bucket[a + l] : 0x7fffffff;
#pragma unroll
        for (int k = 2; k <= 64; k <<= 1) {
#pragma unroll
            for (int j = k >> 1; j >= 1; j >>= 1) {
                int u = __shfl_xor(v, j, 64);
                bool up    = ((l & k) == 0);
                bool lower = ((l & j) == 0);
                int mn = min(v, u), mx = max(v, u);
                v = (up == lower) ? mn : mx;
            }
        }
        if (l < deg) bucket[a + l] = v;
    } else if (l == 0) {
        // fallback (deg>64 essentially impossible for this graph, kept for correctness)
        for (int i = a + 1; i < a + deg; i++) {
            int key = bucket[i];
            int j = i - 1;
            while (j >= a && bucket[j] > key) { bucket[j + 1] = bucket[j]; j--; }
            bucket[j + 1] = key;
        }
    }
}

// ---------------- fat kernel: gemm1 (blocks < GEMM_BLOCKS) || scatter (rest) ----------------
// gemm part: thread = (1 node, 1 head); block = 64 nodes. W read from global (L1 broadcast:
// 16 lanes per wave share each W address). Only the transposed x tile lives in LDS (8.7 KB).
__global__ __launch_bounds__(256) void fat_kernel(const float* __restrict__ x,
                                                  const float* __restrict__ W1,
                                                  const float* __restrict__ asrc1,
                                                  const float* __restrict__ adst1,
                                                  __half* __restrict__ h1,
                                                  float* __restrict__ as1,
                                                  float* __restrict__ ad1,
                                                  const int* __restrict__ ei,
                                                  int* __restrict__ fill,
                                                  int* __restrict__ bucket) {
    __shared__ __align__(16) float xs[32 * 68];  // [kk][node_local], pad 68

    if (blockIdx.x >= GEMM_BLOCKS) {
        // ---- scatter part ----
        int e = (blockIdx.x - GEMM_BLOCKS) * 256 + threadIdx.x;
        if (e >= E_TOT) return;
        int s, d;
        if (e < N_EDGES) { s = ei[e]; d = ei[N_EDGES + e]; }
        else             { s = d = e - N_EDGES; }
        int pos = atomicAdd(&fill[d], 1);
        bucket[pos] = s;
        return;
    }

    // ---- gemm part ----
    const int tid = threadIdx.x;
    const int nl = tid >> 2;         // node local 0..63
    const int head = tid & 3;
    const int base = blockIdx.x * GBLK;
    const int node = base + nl;

    float acc[32];
#pragma unroll
    for (int j = 0; j < 32; j++) acc[j] = 0.f;

    for (int kt = 0; kt < 4; kt++) {
        __syncthreads();
        // stage 64 nodes x 32 k, transposed: 512 float4 loads, 2 per thread
#pragma unroll
        for (int it = 0; it < 2; it++) {
            int idx = tid + it * 256;          // 0..511
            int row = idx >> 3, c4 = idx & 7;  // row 0..63, c4 0..7
            int n2 = base + row;
            float4 v = make_float4(0.f, 0.f, 0.f, 0.f);
            if (n2 < N_NODES)
                v = *(const float4*)(x + (size_t)n2 * 128 + kt * 32 + c4 * 4);
            xs[(c4 * 4 + 0) * 68 + row] = v.x;
            xs[(c4 * 4 + 1) * 68 + row] = v.y;
            xs[(c4 * 4 + 2) * 68 + row] = v.z;
            xs[(c4 * 4 + 3) * 68 + row] = v.w;
        }
        __syncthreads();

#pragma unroll 2
        for (int kk = 0; kk < 32; kk++) {
            float xv = xs[kk * 68 + nl];
            const float4* wrow = (const float4*)(W1 + (size_t)(kt * 32 + kk) * 128 + head * 32);
#pragma unroll
            for (int j4 = 0; j4 < 8; j4++) {
                float4 wv = wrow[j4];
                acc[j4 * 4 + 0] += xv * wv.x;
                acc[j4 * 4 + 1] += xv * wv.y;
                acc[j4 * 4 + 2] += xv * wv.z;
                acc[j4 * 4 + 3] += xv * wv.w;
            }
        }
    }

    if (node >= N_NODES) return;

    // h1 (fp16) write: 32 halfs = 64 B contiguous per thread, coalesced across threads
    __half2 hp[16];
#pragma unroll
    for (int j = 0; j < 16; j++)
        hp[j] = __floats2half2_rn(acc[2 * j], acc[2 * j + 1]);
    float4* dst = (float4*)(h1 + (size_t)node * 128 + head * 32);
#pragma unroll
    for (int j = 0; j < 4; j++)
        dst[j] = ((float4*)hp)[j];

    // attention half-dots
    float sa = 0.f, da = 0.f;
#pragma unroll
    for (int j = 0; j < 32; j++) {
        float v = acc[j];
        sa += v * asrc1[head * 32 + j];
        da += v * adst1[head * 32 + j];
    }
    as1[node * 4 + head] = sa;
    ad1[node * 4 + head] = da;
}

// ---------------- layer 1 aggregation (+bias, ELU, layer-2 projection) ----------------
// one wave per dst node; lane l owns channels 2l, 2l+1 (head = l>>4).
// softmax without max-subtract (logits bounded); 4-way unrolled gather.
__global__ __launch_bounds__(256) void agg1_kernel(const __half* __restrict__ h1,
                                                   const float* __restrict__ as1,
                                                   const float* __restrict__ ad1,
                                                   const int* __restrict__ offs,
                                                   const int* __restrict__ bucket,
                                                   const float* __restrict__ b1,
                                                   const float* __restrict__ W2,
                                                   float* __restrict__ h2s) {
    int w = threadIdx.x >> 6, l = threadIdx.x & 63;
    int node = blockIdx.x * 4 + w;
    if (node >= N_NODES) return;
    int head = l >> 4;
    float adh = ad1[node * 4 + head];
    int a = offs[node];
    int deg = offs[node + 1] - a;

    float sx = 0.f, ax = 0.f, ay = 0.f;
    int i = 0;
    for (; i + 4 <= deg; i += 4) {
        int s0 = bucket[a + i + 0];
        int s1 = bucket[a + i + 1];
        int s2 = bucket[a + i + 2];
        int s3 = bucket[a + i + 3];
        float e0 = as1[s0 * 4 + head] + adh;
        float e1 = as1[s1 * 4 + head] + adh;
        float e2 = as1[s2 * 4 + head] + adh;
        float e3 = as1[s3 * 4 + head] + adh;
        __half2 v0 = ((const __half2*)(h1 + (size_t)s0 * 128))[l];
        __half2 v1 = ((const __half2*)(h1 + (size_t)s1 * 128))[l];
        __half2 v2 = ((const __half2*)(h1 + (size_t)s2 * 128))[l];
        __half2 v3 = ((const __half2*)(h1 + (size_t)s3 * 128))[l];
        e0 = (e0 > 0.f) ? e0 : 0.2f * e0;
        e1 = (e1 > 0.f) ? e1 : 0.2f * e1;
        e2 = (e2 > 0.f) ? e2 : 0.2f * e2;
        e3 = (e3 > 0.f) ? e3 : 0.2f * e3;
        float x0 = __expf(e0), x1 = __expf(e1), x2e = __expf(e2), x3 = __expf(e3);
        float2 f0 = __half22float2(v0);
        float2 f1 = __half22float2(v1);
        float2 f2 = __half22float2(v2);
        float2 f3 = __half22float2(v3);
        sx += (x0 + x1) + (x2e + x3);
        ax += x0 * f0.x + x1 * f1.x + x2e * f2.x + x3 * f3.x;
        ay += x0 * f0.y + x1 * f1.y + x2e * f2.y + x3 * f3.y;
    }
    for (; i < deg; i++) {
        int s = bucket[a + i];
        float e = as1[s * 4 + head] + adh;
        e = (e > 0.f) ? e : 0.2f * e;
        float ex = __expf(e);
        float2 f = __half22float2(((const __half2*)(h1 + (size_t)s * 128))[l]);
        sx += ex;
        ax += ex * f.x;
        ay += ex * f.y;
    }
    float r = 1.f / (sx + 1e-16f);
    float2 bv = ((const float2*)b1)[l];
    float ox = ax * r + bv.x;
    float oy = ay * r + bv.y;
    // ELU
    float xx = (ox > 0.f) ? ox : (__expf(ox) - 1.f);
    float xy = (oy > 0.f) ? oy : (__expf(oy) - 1.f);
    // layer-2 linear: h2s[node] = elu(out1) . W2
    float2 wv = ((const float2*)W2)[l];
    float p = xx * wv.x + xy * wv.y;
#pragma unroll
    for (int o = 32; o > 0; o >>= 1) p += __shfl_xor(p, o, 64);
    if (l == 0) h2s[node] = p;
}

// ---------------- layer 2 aggregation ----------------
__global__ __launch_bounds__(256) void agg2_kernel(const float* __restrict__ h2s,
                                                   const int* __restrict__ offs,
                                                   const int* __restrict__ bucket,
                                                   const float* __restrict__ asrc2,
                                                   const float* __restrict__ adst2,
                                                   const float* __restrict__ b2,
                                                   float* __restrict__ out) {
    int w = threadIdx.x >> 6, l = threadIdx.x & 63;
    int node = blockIdx.x * 4 + w;
    if (node >= N_NODES) return;
    float asc = asrc2[0], adc = adst2[0], bias = b2[0];
    float adn = h2s[node] * adc;
    int a = offs[node], b = offs[node + 1];
    float sx = 0.f, sw = 0.f;
    for (int i = a + l; i < b; i += 64) {
        float hs = h2s[bucket[i]];
        float e = hs * asc + adn;
        e = (e > 0.f) ? e : 0.2f * e;
        float ex = __expf(e);
        sx += ex;
        sw += ex * hs;
    }
#pragma unroll
    for (int o = 32; o > 0; o >>= 1) {
        sx += __shfl_xor(sx, o, 64);
        sw += __shfl_xor(sw, o, 64);
    }
    if (l == 0) out[node] = sw / (sx + 1e-16f) + bias;
}

// ---------------- launch ----------------

extern "C" void kernel_launch(void* const* d_in, const int* in_sizes, int n_in,
                              void* d_out, int out_size, void* d_ws, size_t ws_size,
                              hipStream_t stream) {
    const float* x     = (const float*)d_in[0];
    const int*   ei    = (const int*)d_in[1];
    const float* W1    = (const float*)d_in[2];
    const float* asrc1 = (const float*)d_in[3];
    const float* adst1 = (const float*)d_in[4];
    const float* b1    = (const float*)d_in[5];
    const float* W2    = (const float*)d_in[6];
    const float* asrc2 = (const float*)d_in[7];
    const float* adst2 = (const float*)d_in[8];
    const float* b2    = (const float*)d_in[9];
    float* out = (float*)d_out;

    char* ws = (char*)d_ws;
    size_t o = 0;
    auto alloc = [&](size_t bytes) -> void* {
        void* p = ws + o;
        o += (bytes + 255) & ~(size_t)255;
        return p;
    };
    int* counts  = (int*)alloc((size_t)N_NODES * 4);
    int* offs    = (int*)alloc((size_t)(N_NODES + 1) * 4);
    int* fill    = (int*)alloc((size_t)N_NODES * 4);
    int* bucket  = (int*)alloc((size_t)E_TOT * 4);
    __half* h1   = (__half*)alloc((size_t)N_NODES * 128 * 2);
    float* as1   = (float*)alloc((size_t)N_NODES * 4 * 4);
    float* ad1   = (float*)alloc((size_t)N_NODES * 4 * 4);
    float* h2s   = (float*)alloc((size_t)N_NODES * 4);
    int* localScan = (int*)alloc((size_t)N_NODES * 4);
    int* blockSums = (int*)alloc((size_t)SCAN_BLOCKS * 4);
    int* blockBase = (int*)alloc((size_t)256 * 4);

    hipMemsetAsync(counts, 0, (size_t)N_NODES * 4, stream);

    hist_kernel<<<(E_TOT + 255) / 256, 256, 0, stream>>>(ei, counts);
    scan1_kernel<<<SCAN_BLOCKS, 256, 0, stream>>>(counts, localScan, blockSums);
    scan2_kernel<<<1, 256, 0, stream>>>(blockSums, blockBase);
    scan3_kernel<<<SCAN_BLOCKS, 256, 0, stream>>>(localScan, blockBase, offs, fill);

    fat_kernel<<<GEMM_BLOCKS + SCAT_BLOCKS, 256, 0, stream>>>(
        x, W1, asrc1, adst1, h1, as1, ad1, ei, fill, bucket);

    sort_kernel<<<(N_NODES * 64 + 255) / 256, 256, 0, stream>>>(offs, bucket);

    agg1_kernel<<<(N_NODES + 3) / 4, 256, 0, stream>>>(
        h1, as1, ad1, offs, bucket, b1, W2, h2s);

    agg2_kernel<<<(N_NODES + 3) / 4, 256, 0, stream>>>(
        h2s, offs, bucket, asrc2, adst2, b2, out);
}

// Round 6
// 212.028 us; speedup vs baseline: 2.7381x; 2.7381x over previous
//
#include <hip/hip_runtime.h>
#include <hip/hip_bf16.h>
#include <hip/hip_fp16.h>

#define N_NODES 50000
#define N_EDGES 800000
#define E_TOT   850000   // + self loops
#define SCAN_BLOCKS 196  // ceil(50000/256)
#define GBLK 64          // nodes per gemm block
#define GEMM_BLOCKS 782  // ceil(50000/64)

// ---------------- CSR build ----------------

__global__ void hist_kernel(const int* __restrict__ ei, int* __restrict__ counts) {
    int e = blockIdx.x * blockDim.x + threadIdx.x;
    if (e >= E_TOT) return;
    int d = (e < N_EDGES) ? ei[N_EDGES + e] : (e - N_EDGES);
    atomicAdd(&counts[d], 1);
}

// hierarchical exclusive scan: local 256-scan -> block-sum scan -> add base
__global__ __launch_bounds__(256) void scan1_kernel(const int* __restrict__ counts,
                                                    int* __restrict__ localScan,
                                                    int* __restrict__ blockSums) {
    __shared__ int tmp[256];
    int t = threadIdx.x, i = blockIdx.x * 256 + t;
    int v = (i < N_NODES) ? counts[i] : 0;
    tmp[t] = v;
    __syncthreads();
    for (int d = 1; d < 256; d <<= 1) {
        int u = (t >= d) ? tmp[t - d] : 0;
        __syncthreads();
        tmp[t] += u;
        __syncthreads();
    }
    if (i < N_NODES) localScan[i] = tmp[t] - v;  // exclusive
    if (t == 255) blockSums[blockIdx.x] = tmp[t];
}

__global__ __launch_bounds__(256) void scan2_kernel(const int* __restrict__ blockSums,
                                                    int* __restrict__ blockBase) {
    __shared__ int tmp[256];
    int t = threadIdx.x;
    int v = (t < SCAN_BLOCKS) ? blockSums[t] : 0;
    tmp[t] = v;
    __syncthreads();
    for (int d = 1; d < 256; d <<= 1) {
        int u = (t >= d) ? tmp[t - d] : 0;
        __syncthreads();
        tmp[t] += u;
        __syncthreads();
    }
    blockBase[t] = tmp[t] - v;  // exclusive
}

__global__ void scan3_kernel(const int* __restrict__ localScan,
                             const int* __restrict__ blockBase,
                             int* __restrict__ offs, int* __restrict__ fill) {
    int i = blockIdx.x * 256 + threadIdx.x;
    if (i < N_NODES) {
        int o = localScan[i] + blockBase[i >> 8];
        offs[i] = o;
        fill[i] = o;
    }
    if (i == 0) offs[N_NODES] = E_TOT;
}

// scatter: 4 edges per thread -> 4 independent atomic+store chains in flight.
// E_TOT % 4 == 0 and N_EDGES % 4 == 0, so each thread's 4 edges are homogeneous.
__global__ void scatter_kernel(const int* __restrict__ ei, int* __restrict__ fill,
                               int* __restrict__ bucket) {
    int e = (blockIdx.x * blockDim.x + threadIdx.x) * 4;
    if (e >= E_TOT) return;
    int s0, s1, s2, s3, d0, d1, d2, d3;
    if (e < N_EDGES) {
        int4 sv = *(const int4*)(ei + e);
        int4 dv = *(const int4*)(ei + N_EDGES + e);
        s0 = sv.x; s1 = sv.y; s2 = sv.z; s3 = sv.w;
        d0 = dv.x; d1 = dv.y; d2 = dv.z; d3 = dv.w;
    } else {
        int b = e - N_EDGES;
        s0 = d0 = b; s1 = d1 = b + 1; s2 = d2 = b + 2; s3 = d3 = b + 3;
    }
    int p0 = atomicAdd(&fill[d0], 1);
    int p1 = atomicAdd(&fill[d1], 1);
    int p2 = atomicAdd(&fill[d2], 1);
    int p3 = atomicAdd(&fill[d3], 1);
    bucket[p0] = s0;
    bucket[p1] = s1;
    bucket[p2] = s2;
    bucket[p3] = s3;
}

// deterministic ordering: sort each node's bucket by src id.
// one WAVE per node; <=64 elements sorted in-register via bitonic network.
__global__ __launch_bounds__(256) void sort_kernel(const int* __restrict__ offs,
                                                   int* __restrict__ bucket) {
    int w = (blockIdx.x * blockDim.x + threadIdx.x) >> 6;
    int l = threadIdx.x & 63;
    if (w >= N_NODES) return;
    int a = offs[w];
    int deg = offs[w + 1] - a;
    if (deg <= 1) return;
    if (deg <= 64) {
        int v = (l < deg) ? bucket[a + l] : 0x7fffffff;
#pragma unroll
        for (int k = 2; k <= 64; k <<= 1) {
#pragma unroll
            for (int j = k >> 1; j >= 1; j >>= 1) {
                int u = __shfl_xor(v, j, 64);
                bool up    = ((l & k) == 0);
                bool lower = ((l & j) == 0);
                int mn = min(v, u), mx = max(v, u);
                v = (up == lower) ? mn : mx;
            }
        }
        if (l < deg) bucket[a + l] = v;
    } else if (l == 0) {
        // fallback (deg>64 essentially impossible for this graph, kept for correctness)
        for (int i = a + 1; i < a + deg; i++) {
            int key = bucket[i];
            int j = i - 1;
            while (j >= a && bucket[j] > key) { bucket[j + 1] = bucket[j]; j--; }
            bucket[j + 1] = key;
        }
    }
}

// ---------------- layer 1 GEMM: h1 = x @ W1 (fp16 out) + per-(node,head) attn dots ----
// wave = one head (wave-uniform -> W1 reads become scalar s_loads through the
// constant cache; FMA is v_fmac vacc, s_w, v_x). lane = one node. block = 64 nodes.
// LDS holds only the transposed x tile (8.5 KB) -> many blocks/CU.
__global__ __launch_bounds__(256) void gemm1_kernel(const float* __restrict__ x,
                                                    const float* __restrict__ W1,
                                                    const float* __restrict__ asrc1,
                                                    const float* __restrict__ adst1,
                                                    __half* __restrict__ h1,
                                                    float* __restrict__ as1,
                                                    float* __restrict__ ad1) {
    __shared__ float xs[32 * 65];   // [kk][node_local], pad 65 -> conflict-free

    const int tid  = threadIdx.x;
    const int lane = tid & 63;
    const int head = __builtin_amdgcn_readfirstlane(tid >> 6);  // wave-uniform
    const int base = blockIdx.x * GBLK;
    const int node = base + lane;

    const float* __restrict__ wh = W1 + head * 32;       // uniform base

    float acc[32];
#pragma unroll
    for (int j = 0; j < 32; j++) acc[j] = 0.f;

    for (int kt = 0; kt < 4; kt++) {
        __syncthreads();
        // stage 64 nodes x 32 k, transposed: 512 float4 loads, 2 per thread
#pragma unroll
        for (int it = 0; it < 2; it++) {
            int idx = tid + it * 256;          // 0..511
            int row = idx >> 3, c4 = idx & 7;  // row 0..63, c4 0..7
            int n2 = base + row;
            float4 v = make_float4(0.f, 0.f, 0.f, 0.f);
            if (n2 < N_NODES)
                v = *(const float4*)(x + (size_t)n2 * 128 + kt * 32 + c4 * 4);
            xs[(c4 * 4 + 0) * 65 + row] = v.x;
            xs[(c4 * 4 + 1) * 65 + row] = v.y;
            xs[(c4 * 4 + 2) * 65 + row] = v.z;
            xs[(c4 * 4 + 3) * 65 + row] = v.w;
        }
        __syncthreads();

        for (int kk = 0; kk < 32; kk++) {
            float xv = xs[kk * 65 + lane];
            const float* __restrict__ wr = wh + (size_t)(kt * 32 + kk) * 128; // uniform
#pragma unroll
            for (int j = 0; j < 32; j++)
                acc[j] += xv * wr[j];
        }
    }

    if (node >= N_NODES) return;

    // h1 (fp16): 32 halfs = 64 B contiguous per lane
    __half2 hp[16];
#pragma unroll
    for (int j = 0; j < 16; j++)
        hp[j] = __floats2half2_rn(acc[2 * j], acc[2 * j + 1]);
    float4* dst = (float4*)(h1 + (size_t)node * 128 + head * 32);
#pragma unroll
    for (int j = 0; j < 4; j++)
        dst[j] = ((float4*)hp)[j];

    // attention half-dots (asrc1/adst1 reads also wave-uniform -> s_load)
    float sa = 0.f, da = 0.f;
#pragma unroll
    for (int j = 0; j < 32; j++) {
        float v = acc[j];
        sa += v * asrc1[head * 32 + j];
        da += v * adst1[head * 32 + j];
    }
    as1[node * 4 + head] = sa;
    ad1[node * 4 + head] = da;
}

// ---------------- layer 1 aggregation (+bias, ELU, layer-2 projection) ----------------
// one wave per dst node; lane l owns channels 2l, 2l+1 (head = l>>4).
// softmax without max-subtract (logits bounded); 4-way unrolled gather.
__global__ __launch_bounds__(256) void agg1_kernel(const __half* __restrict__ h1,
                                                   const float* __restrict__ as1,
                                                   const float* __restrict__ ad1,
                                                   const int* __restrict__ offs,
                                                   const int* __restrict__ bucket,
                                                   const float* __restrict__ b1,
                                                   const float* __restrict__ W2,
                                                   float* __restrict__ h2s) {
    int w = threadIdx.x >> 6, l = threadIdx.x & 63;
    int node = blockIdx.x * 4 + w;
    if (node >= N_NODES) return;
    int head = l >> 4;
    float adh = ad1[node * 4 + head];
    int a = offs[node];
    int deg = offs[node + 1] - a;

    float sx = 0.f, ax = 0.f, ay = 0.f;
    int i = 0;
    for (; i + 4 <= deg; i += 4) {
        int s0 = bucket[a + i + 0];
        int s1 = bucket[a + i + 1];
        int s2 = bucket[a + i + 2];
        int s3 = bucket[a + i + 3];
        float e0 = as1[s0 * 4 + head] + adh;
        float e1 = as1[s1 * 4 + head] + adh;
        float e2 = as1[s2 * 4 + head] + adh;
        float e3 = as1[s3 * 4 + head] + adh;
        __half2 v0 = ((const __half2*)(h1 + (size_t)s0 * 128))[l];
        __half2 v1 = ((const __half2*)(h1 + (size_t)s1 * 128))[l];
        __half2 v2 = ((const __half2*)(h1 + (size_t)s2 * 128))[l];
        __half2 v3 = ((const __half2*)(h1 + (size_t)s3 * 128))[l];
        e0 = (e0 > 0.f) ? e0 : 0.2f * e0;
        e1 = (e1 > 0.f) ? e1 : 0.2f * e1;
        e2 = (e2 > 0.f) ? e2 : 0.2f * e2;
        e3 = (e3 > 0.f) ? e3 : 0.2f * e3;
        float x0 = __expf(e0), x1 = __expf(e1), x2e = __expf(e2), x3 = __expf(e3);
        float2 f0 = __half22float2(v0);
        float2 f1 = __half22float2(v1);
        float2 f2 = __half22float2(v2);
        float2 f3 = __half22float2(v3);
        sx += (x0 + x1) + (x2e + x3);
        ax += x0 * f0.x + x1 * f1.x + x2e * f2.x + x3 * f3.x;
        ay += x0 * f0.y + x1 * f1.y + x2e * f2.y + x3 * f3.y;
    }
    for (; i < deg; i++) {
        int s = bucket[a + i];
        float e = as1[s * 4 + head] + adh;
        e = (e > 0.f) ? e : 0.2f * e;
        float ex = __expf(e);
        float2 f = __half22float2(((const __half2*)(h1 + (size_t)s * 128))[l]);
        sx += ex;
        ax += ex * f.x;
        ay += ex * f.y;
    }
    float r = 1.f / (sx + 1e-16f);
    float2 bv = ((const float2*)b1)[l];
    float ox = ax * r + bv.x;
    float oy = ay * r + bv.y;
    // ELU
    float xx = (ox > 0.f) ? ox : (__expf(ox) - 1.f);
    float xy = (oy > 0.f) ? oy : (__expf(oy) - 1.f);
    // layer-2 linear: h2s[node] = elu(out1) . W2
    float2 wv = ((const float2*)W2)[l];
    float p = xx * wv.x + xy * wv.y;
#pragma unroll
    for (int o = 32; o > 0; o >>= 1) p += __shfl_xor(p, o, 64);
    if (l == 0) h2s[node] = p;
}

// ---------------- layer 2 aggregation ----------------
__global__ __launch_bounds__(256) void agg2_kernel(const float* __restrict__ h2s,
                                                   const int* __restrict__ offs,
                                                   const int* __restrict__ bucket,
                                                   const float* __restrict__ asrc2,
                                                   const float* __restrict__ adst2,
                                                   const float* __restrict__ b2,
                                                   float* __restrict__ out) {
    int w = threadIdx.x >> 6, l = threadIdx.x & 63;
    int node = blockIdx.x * 4 + w;
    if (node >= N_NODES) return;
    float asc = asrc2[0], adc = adst2[0], bias = b2[0];
    float adn = h2s[node] * adc;
    int a = offs[node], b = offs[node + 1];
    float sx = 0.f, sw = 0.f;
    for (int i = a + l; i < b; i += 64) {
        float hs = h2s[bucket[i]];
        float e = hs * asc + adn;
        e = (e > 0.f) ? e : 0.2f * e;
        float ex = __expf(e);
        sx += ex;
        sw += ex * hs;
    }
#pragma unroll
    for (int o = 32; o > 0; o >>= 1) {
        sx += __shfl_xor(sx, o, 64);
        sw += __shfl_xor(sw, o, 64);
    }
    if (l == 0) out[node] = sw / (sx + 1e-16f) + bias;
}

// ---------------- launch ----------------

extern "C" void kernel_launch(void* const* d_in, const int* in_sizes, int n_in,
                              void* d_out, int out_size, void* d_ws, size_t ws_size,
                              hipStream_t stream) {
    const float* x     = (const float*)d_in[0];
    const int*   ei    = (const int*)d_in[1];
    const float* W1    = (const float*)d_in[2];
    const float* asrc1 = (const float*)d_in[3];
    const float* adst1 = (const float*)d_in[4];
    const float* b1    = (const float*)d_in[5];
    const float* W2    = (const float*)d_in[6];
    const float* asrc2 = (const float*)d_in[7];
    const float* adst2 = (const float*)d_in[8];
    const float* b2    = (const float*)d_in[9];
    float* out = (float*)d_out;

    char* ws = (char*)d_ws;
    size_t o = 0;
    auto alloc = [&](size_t bytes) -> void* {
        void* p = ws + o;
        o += (bytes + 255) & ~(size_t)255;
        return p;
    };
    int* counts  = (int*)alloc((size_t)N_NODES * 4);
    int* offs    = (int*)alloc((size_t)(N_NODES + 1) * 4);
    int* fill    = (int*)alloc((size_t)N_NODES * 4);
    int* bucket  = (int*)alloc((size_t)E_TOT * 4);
    __half* h1   = (__half*)alloc((size_t)N_NODES * 128 * 2);
    float* as1   = (float*)alloc((size_t)N_NODES * 4 * 4);
    float* ad1   = (float*)alloc((size_t)N_NODES * 4 * 4);
    float* h2s   = (float*)alloc((size_t)N_NODES * 4);
    int* localScan = (int*)alloc((size_t)N_NODES * 4);
    int* blockSums = (int*)alloc((size_t)SCAN_BLOCKS * 4);
    int* blockBase = (int*)alloc((size_t)256 * 4);

    hipMemsetAsync(counts, 0, (size_t)N_NODES * 4, stream);

    hist_kernel<<<(E_TOT + 255) / 256, 256, 0, stream>>>(ei, counts);
    scan1_kernel<<<SCAN_BLOCKS, 256, 0, stream>>>(counts, localScan, blockSums);
    scan2_kernel<<<1, 256, 0, stream>>>(blockSums, blockBase);
    scan3_kernel<<<SCAN_BLOCKS, 256, 0, stream>>>(localScan, blockBase, offs, fill);
    scatter_kernel<<<(E_TOT / 4 + 255) / 256, 256, 0, stream>>>(ei, fill, bucket);
    sort_kernel<<<(N_NODES * 64 + 255) / 256, 256, 0, stream>>>(offs, bucket);

    gemm1_kernel<<<GEMM_BLOCKS, 256, 0, stream>>>(
        x, W1, asrc1, adst1, h1, as1, ad1);

    agg1_kernel<<<(N_NODES + 3) / 4, 256, 0, stream>>>(
        h1, as1, ad1, offs, bucket, b1, W2, h2s);

    agg2_kernel<<<(N_NODES + 3) / 4, 256, 0, stream>>>(
        h2s, offs, bucket, asrc2, adst2, b2, out);
}

// Round 7
// 197.322 us; speedup vs baseline: 2.9422x; 1.0745x over previous
//
#include <hip/hip_runtime.h>
#include <hip/hip_bf16.h>
#include <hip/hip_fp16.h>

#define N_NODES 50000
#define N_EDGES 800000
#define E_TOT   850000   // + self loops
#define SCAN_BLOCKS 196  // ceil(50000/256)
#define GBLK 64          // nodes per gemm block
#define GEMM_BLOCKS 782  // ceil(50000/64)
#define SCAT_RANGES 8
#define RANGE_SIZE 6250  // 50000/8

// ---------------- CSR build ----------------

__global__ void hist_kernel(const int* __restrict__ ei, int* __restrict__ counts) {
    int e = (blockIdx.x * blockDim.x + threadIdx.x) * 4;
    if (e >= E_TOT) return;
    if (e < N_EDGES) {
        int4 dv = *(const int4*)(ei + N_EDGES + e);
        atomicAdd(&counts[dv.x], 1);
        atomicAdd(&counts[dv.y], 1);
        atomicAdd(&counts[dv.z], 1);
        atomicAdd(&counts[dv.w], 1);
    } else {
        int b = e - N_EDGES;
        atomicAdd(&counts[b + 0], 1);
        atomicAdd(&counts[b + 1], 1);
        atomicAdd(&counts[b + 2], 1);
        atomicAdd(&counts[b + 3], 1);
    }
}

// hierarchical exclusive scan: local 256-scan -> block-sum scan -> add base
__global__ __launch_bounds__(256) void scan1_kernel(const int* __restrict__ counts,
                                                    int* __restrict__ localScan,
                                                    int* __restrict__ blockSums) {
    __shared__ int tmp[256];
    int t = threadIdx.x, i = blockIdx.x * 256 + t;
    int v = (i < N_NODES) ? counts[i] : 0;
    tmp[t] = v;
    __syncthreads();
    for (int d = 1; d < 256; d <<= 1) {
        int u = (t >= d) ? tmp[t - d] : 0;
        __syncthreads();
        tmp[t] += u;
        __syncthreads();
    }
    if (i < N_NODES) localScan[i] = tmp[t] - v;  // exclusive
    if (t == 255) blockSums[blockIdx.x] = tmp[t];
}

__global__ __launch_bounds__(256) void scan2_kernel(const int* __restrict__ blockSums,
                                                    int* __restrict__ blockBase) {
    __shared__ int tmp[256];
    int t = threadIdx.x;
    int v = (t < SCAN_BLOCKS) ? blockSums[t] : 0;
    tmp[t] = v;
    __syncthreads();
    for (int d = 1; d < 256; d <<= 1) {
        int u = (t >= d) ? tmp[t - d] : 0;
        __syncthreads();
        tmp[t] += u;
        __syncthreads();
    }
    blockBase[t] = tmp[t] - v;  // exclusive
}

__global__ void scan3_kernel(const int* __restrict__ localScan,
                             const int* __restrict__ blockBase,
                             int* __restrict__ offs, int* __restrict__ fill) {
    int i = blockIdx.x * 256 + threadIdx.x;
    if (i < N_NODES) {
        int o = localScan[i] + blockBase[i >> 8];
        offs[i] = o;
        fill[i] = o;
    }
    if (i == 0) offs[N_NODES] = E_TOT;
}

// scatter, dst-range partitioned: range r = blockIdx&7 -> all blocks of a range
// land on one XCD (blockIdx%8 round-robin dispatch) -> bucket region stays in
// that XCD's L2 -> full-line write combining instead of 64B/store write-back.
__global__ void scatter_kernel(const int* __restrict__ ei, int* __restrict__ fill,
                               int* __restrict__ bucket) {
    int r = blockIdx.x & (SCAT_RANGES - 1);
    int chunk = blockIdx.x >> 3;
    int e = (chunk * 256 + threadIdx.x) * 4;
    if (e >= E_TOT) return;
    int lo = r * RANGE_SIZE, hi = lo + RANGE_SIZE;
    int s0, s1, s2, s3, d0, d1, d2, d3;
    if (e < N_EDGES) {
        int4 sv = *(const int4*)(ei + e);
        int4 dv = *(const int4*)(ei + N_EDGES + e);
        s0 = sv.x; s1 = sv.y; s2 = sv.z; s3 = sv.w;
        d0 = dv.x; d1 = dv.y; d2 = dv.z; d3 = dv.w;
    } else {
        int b = e - N_EDGES;
        s0 = d0 = b; s1 = d1 = b + 1; s2 = d2 = b + 2; s3 = d3 = b + 3;
    }
    if (d0 >= lo && d0 < hi) { int p = atomicAdd(&fill[d0], 1); bucket[p] = s0; }
    if (d1 >= lo && d1 < hi) { int p = atomicAdd(&fill[d1], 1); bucket[p] = s1; }
    if (d2 >= lo && d2 < hi) { int p = atomicAdd(&fill[d2], 1); bucket[p] = s2; }
    if (d3 >= lo && d3 < hi) { int p = atomicAdd(&fill[d3], 1); bucket[p] = s3; }
}

// deterministic ordering: sort each node's bucket by src id.
// one WAVE per node; <=64 elements sorted in-register via bitonic network.
__global__ __launch_bounds__(256) void sort_kernel(const int* __restrict__ offs,
                                                   int* __restrict__ bucket) {
    int w = (blockIdx.x * blockDim.x + threadIdx.x) >> 6;
    int l = threadIdx.x & 63;
    if (w >= N_NODES) return;
    int a = offs[w];
    int deg = offs[w + 1] - a;
    if (deg <= 1) return;
    if (deg <= 64) {
        int v = (l < deg) ? bucket[a + l] : 0x7fffffff;
#pragma unroll
        for (int k = 2; k <= 64; k <<= 1) {
#pragma unroll
            for (int j = k >> 1; j >= 1; j >>= 1) {
                int u = __shfl_xor(v, j, 64);
                bool up    = ((l & k) == 0);
                bool lower = ((l & j) == 0);
                int mn = min(v, u), mx = max(v, u);
                v = (up == lower) ? mn : mx;
            }
        }
        if (l < deg) bucket[a + l] = v;
    } else if (l == 0) {
        // fallback (deg>64 essentially impossible for this graph, kept for correctness)
        for (int i = a + 1; i < a + deg; i++) {
            int key = bucket[i];
            int j = i - 1;
            while (j >= a && bucket[j] > key) { bucket[j + 1] = bucket[j]; j--; }
            bucket[j + 1] = key;
        }
    }
}

// ---------------- layer 1 GEMM: h1 = x @ W1 (fp16 out) + per-(node,head) attn dots ----
// block = 512 threads = 8 waves; wave w: head = w>>1, colhalf = w&1 (wave-uniform ->
// W reads are s_loads through the scalar cache). lane = node. acc[16]/thread.
// 782 blocks x 8 waves = 6256 waves (~6/SIMD) for latency hiding.
__global__ __launch_bounds__(512) void gemm1_kernel(const float* __restrict__ x,
                                                    const float* __restrict__ W1,
                                                    const float* __restrict__ asrc1,
                                                    const float* __restrict__ adst1,
                                                    __half* __restrict__ h1,
                                                    float* __restrict__ as1,
                                                    float* __restrict__ ad1) {
    __shared__ float xs[32 * 65];     // [kk][node_local], pad 65 -> conflict-free
    __shared__ float sredA[8 * 64];   // per-wave partial a_src dots
    __shared__ float sredB[8 * 64];   // per-wave partial a_dst dots

    const int tid  = threadIdx.x;
    const int lane = tid & 63;
    const int w    = tid >> 6;                                    // 0..7
    const int head = __builtin_amdgcn_readfirstlane(w >> 1);      // wave-uniform
    const int ch   = __builtin_amdgcn_readfirstlane(w & 1);       // col half
    const int base = blockIdx.x * GBLK;
    const int node = base + lane;

    const float* __restrict__ wh = W1 + head * 32 + ch * 16;      // uniform base

    float acc[16];
#pragma unroll
    for (int j = 0; j < 16; j++) acc[j] = 0.f;

    for (int kt = 0; kt < 4; kt++) {
        __syncthreads();
        // stage 64 nodes x 32 k, transposed: 512 float4 loads, 1 per thread
        {
            int row = tid >> 3, c4 = tid & 7;  // row 0..63, c4 0..7
            int n2 = base + row;
            float4 v = make_float4(0.f, 0.f, 0.f, 0.f);
            if (n2 < N_NODES)
                v = *(const float4*)(x + (size_t)n2 * 128 + kt * 32 + c4 * 4);
            xs[(c4 * 4 + 0) * 65 + row] = v.x;
            xs[(c4 * 4 + 1) * 65 + row] = v.y;
            xs[(c4 * 4 + 2) * 65 + row] = v.z;
            xs[(c4 * 4 + 3) * 65 + row] = v.w;
        }
        __syncthreads();

#pragma unroll 4
        for (int kk = 0; kk < 32; kk++) {
            float xv = xs[kk * 65 + lane];
            const float* __restrict__ wr = wh + (size_t)(kt * 32 + kk) * 128; // uniform
#pragma unroll
            for (int j = 0; j < 16; j++)
                acc[j] += xv * wr[j];
        }
    }

    // h1 (fp16): 16 halfs = 32 B contiguous per lane
    if (node < N_NODES) {
        __half2 hp[8];
#pragma unroll
        for (int j = 0; j < 8; j++)
            hp[j] = __floats2half2_rn(acc[2 * j], acc[2 * j + 1]);
        float4* dst = (float4*)(h1 + (size_t)node * 128 + head * 32 + ch * 16);
        dst[0] = ((float4*)hp)[0];
        dst[1] = ((float4*)hp)[1];
    }

    // attention half-dots: 16-col partials, combined across the two col-half waves
    float sa = 0.f, da = 0.f;
#pragma unroll
    for (int j = 0; j < 16; j++) {
        float v = acc[j];
        sa += v * asrc1[head * 32 + ch * 16 + j];
        da += v * adst1[head * 32 + ch * 16 + j];
    }
    sredA[w * 64 + lane] = sa;
    sredB[w * 64 + lane] = da;
    __syncthreads();
    if (tid < 256) {
        int hh = tid >> 6;
        int nd = base + lane;
        if (nd < N_NODES) {
            as1[nd * 4 + hh] = sredA[(hh * 2) * 64 + lane] + sredA[(hh * 2 + 1) * 64 + lane];
            ad1[nd * 4 + hh] = sredB[(hh * 2) * 64 + lane] + sredB[(hh * 2 + 1) * 64 + lane];
        }
    }
}

// ---------------- layer 1 aggregation (+bias, ELU, layer-2 projection) ----------------
// one wave per dst node; lane l owns channels 2l, 2l+1 (head = l>>4).
// softmax without max-subtract (logits bounded); 4-way unrolled gather.
__global__ __launch_bounds__(256) void agg1_kernel(const __half* __restrict__ h1,
                                                   const float* __restrict__ as1,
                                                   const float* __restrict__ ad1,
                                                   const int* __restrict__ offs,
                                                   const int* __restrict__ bucket,
                                                   const float* __restrict__ b1,
                                                   const float* __restrict__ W2,
                                                   float* __restrict__ h2s) {
    int w = threadIdx.x >> 6, l = threadIdx.x & 63;
    int node = blockIdx.x * 4 + w;
    if (node >= N_NODES) return;
    int head = l >> 4;
    float adh = ad1[node * 4 + head];
    int a = offs[node];
    int deg = offs[node + 1] - a;

    float sx = 0.f, ax = 0.f, ay = 0.f;
    int i = 0;
    for (; i + 4 <= deg; i += 4) {
        int s0 = bucket[a + i + 0];
        int s1 = bucket[a + i + 1];
        int s2 = bucket[a + i + 2];
        int s3 = bucket[a + i + 3];
        float e0 = as1[s0 * 4 + head] + adh;
        float e1 = as1[s1 * 4 + head] + adh;
        float e2 = as1[s2 * 4 + head] + adh;
        float e3 = as1[s3 * 4 + head] + adh;
        __half2 v0 = ((const __half2*)(h1 + (size_t)s0 * 128))[l];
        __half2 v1 = ((const __half2*)(h1 + (size_t)s1 * 128))[l];
        __half2 v2 = ((const __half2*)(h1 + (size_t)s2 * 128))[l];
        __half2 v3 = ((const __half2*)(h1 + (size_t)s3 * 128))[l];
        e0 = (e0 > 0.f) ? e0 : 0.2f * e0;
        e1 = (e1 > 0.f) ? e1 : 0.2f * e1;
        e2 = (e2 > 0.f) ? e2 : 0.2f * e2;
        e3 = (e3 > 0.f) ? e3 : 0.2f * e3;
        float x0 = __expf(e0), x1 = __expf(e1), x2e = __expf(e2), x3 = __expf(e3);
        float2 f0 = __half22float2(v0);
        float2 f1 = __half22float2(v1);
        float2 f2 = __half22float2(v2);
        float2 f3 = __half22float2(v3);
        sx += (x0 + x1) + (x2e + x3);
        ax += x0 * f0.x + x1 * f1.x + x2e * f2.x + x3 * f3.x;
        ay += x0 * f0.y + x1 * f1.y + x2e * f2.y + x3 * f3.y;
    }
    for (; i < deg; i++) {
        int s = bucket[a + i];
        float e = as1[s * 4 + head] + adh;
        e = (e > 0.f) ? e : 0.2f * e;
        float ex = __expf(e);
        float2 f = __half22float2(((const __half2*)(h1 + (size_t)s * 128))[l]);
        sx += ex;
        ax += ex * f.x;
        ay += ex * f.y;
    }
    float r = 1.f / (sx + 1e-16f);
    float2 bv = ((const float2*)b1)[l];
    float ox = ax * r + bv.x;
    float oy = ay * r + bv.y;
    // ELU
    float xx = (ox > 0.f) ? ox : (__expf(ox) - 1.f);
    float xy = (oy > 0.f) ? oy : (__expf(oy) - 1.f);
    // layer-2 linear: h2s[node] = elu(out1) . W2
    float2 wv = ((const float2*)W2)[l];
    float p = xx * wv.x + xy * wv.y;
#pragma unroll
    for (int o = 32; o > 0; o >>= 1) p += __shfl_xor(p, o, 64);
    if (l == 0) h2s[node] = p;
}

// ---------------- layer 2 aggregation ----------------
__global__ __launch_bounds__(256) void agg2_kernel(const float* __restrict__ h2s,
                                                   const int* __restrict__ offs,
                                                   const int* __restrict__ bucket,
                                                   const float* __restrict__ asrc2,
                                                   const float* __restrict__ adst2,
                                                   const float* __restrict__ b2,
                                                   float* __restrict__ out) {
    int w = threadIdx.x >> 6, l = threadIdx.x & 63;
    int node = blockIdx.x * 4 + w;
    if (node >= N_NODES) return;
    float asc = asrc2[0], adc = adst2[0], bias = b2[0];
    float adn = h2s[node] * adc;
    int a = offs[node], b = offs[node + 1];
    float sx = 0.f, sw = 0.f;
    for (int i = a + l; i < b; i += 64) {
        float hs = h2s[bucket[i]];
        float e = hs * asc + adn;
        e = (e > 0.f) ? e : 0.2f * e;
        float ex = __expf(e);
        sx += ex;
        sw += ex * hs;
    }
#pragma unroll
    for (int o = 32; o > 0; o >>= 1) {
        sx += __shfl_xor(sx, o, 64);
        sw += __shfl_xor(sw, o, 64);
    }
    if (l == 0) out[node] = sw / (sx + 1e-16f) + bias;
}

// ---------------- launch ----------------

extern "C" void kernel_launch(void* const* d_in, const int* in_sizes, int n_in,
                              void* d_out, int out_size, void* d_ws, size_t ws_size,
                              hipStream_t stream) {
    const float* x     = (const float*)d_in[0];
    const int*   ei    = (const int*)d_in[1];
    const float* W1    = (const float*)d_in[2];
    const float* asrc1 = (const float*)d_in[3];
    const float* adst1 = (const float*)d_in[4];
    const float* b1    = (const float*)d_in[5];
    const float* W2    = (const float*)d_in[6];
    const float* asrc2 = (const float*)d_in[7];
    const float* adst2 = (const float*)d_in[8];
    const float* b2    = (const float*)d_in[9];
    float* out = (float*)d_out;

    char* ws = (char*)d_ws;
    size_t o = 0;
    auto alloc = [&](size_t bytes) -> void* {
        void* p = ws + o;
        o += (bytes + 255) & ~(size_t)255;
        return p;
    };
    int* counts  = (int*)alloc((size_t)N_NODES * 4);
    int* offs    = (int*)alloc((size_t)(N_NODES + 1) * 4);
    int* fill    = (int*)alloc((size_t)N_NODES * 4);
    int* bucket  = (int*)alloc((size_t)E_TOT * 4);
    __half* h1   = (__half*)alloc((size_t)N_NODES * 128 * 2);
    float* as1   = (float*)alloc((size_t)N_NODES * 4 * 4);
    float* ad1   = (float*)alloc((size_t)N_NODES * 4 * 4);
    float* h2s   = (float*)alloc((size_t)N_NODES * 4);
    int* localScan = (int*)alloc((size_t)N_NODES * 4);
    int* blockSums = (int*)alloc((size_t)SCAN_BLOCKS * 4);
    int* blockBase = (int*)alloc((size_t)256 * 4);

    hipMemsetAsync(counts, 0, (size_t)N_NODES * 4, stream);

    hist_kernel<<<(E_TOT / 4 + 255) / 256, 256, 0, stream>>>(ei, counts);
    scan1_kernel<<<SCAN_BLOCKS, 256, 0, stream>>>(counts, localScan, blockSums);
    scan2_kernel<<<1, 256, 0, stream>>>(blockSums, blockBase);
    scan3_kernel<<<SCAN_BLOCKS, 256, 0, stream>>>(localScan, blockBase, offs, fill);

    int scat_chunks = (E_TOT / 4 + 255) / 256;  // 831
    scatter_kernel<<<scat_chunks * SCAT_RANGES, 256, 0, stream>>>(ei, fill, bucket);

    sort_kernel<<<(N_NODES * 64 + 255) / 256, 256, 0, stream>>>(offs, bucket);

    gemm1_kernel<<<GEMM_BLOCKS, 512, 0, stream>>>(
        x, W1, asrc1, adst1, h1, as1, ad1);

    agg1_kernel<<<(N_NODES + 3) / 4, 256, 0, stream>>>(
        h1, as1, ad1, offs, bucket, b1, W2, h2s);

    agg2_kernel<<<(N_NODES + 3) / 4, 256, 0, stream>>>(
        h2s, offs, bucket, asrc2, adst2, b2, out);
}

// Round 8
// 175.833 us; speedup vs baseline: 3.3017x; 1.1222x over previous
//
#include <hip/hip_runtime.h>
#include <hip/hip_bf16.h>
#include <hip/hip_fp16.h>

#define N_NODES 50000
#define N_EDGES 800000
#define E_TOT   850000   // + self loops
#define SCAN_BLOCKS 196  // ceil(50000/256)
#define GBLK 64          // nodes per gemm block
#define GEMM_BLOCKS 782  // ceil(50000/64)
#define SCAT_RANGES 8
#define RANGE_SIZE 6250  // 50000/8
#define SCAT_CHUNKS 416  // ceil(850000/2048), 2048 edges per 512-thr block
#define SCAT_BLOCKS (SCAT_CHUNKS * SCAT_RANGES)

// ---------------- CSR build ----------------

__global__ void hist_kernel(const int* __restrict__ ei, int* __restrict__ counts) {
    int e = (blockIdx.x * blockDim.x + threadIdx.x) * 4;
    if (e >= E_TOT) return;
    if (e < N_EDGES) {
        int4 dv = *(const int4*)(ei + N_EDGES + e);
        atomicAdd(&counts[dv.x], 1);
        atomicAdd(&counts[dv.y], 1);
        atomicAdd(&counts[dv.z], 1);
        atomicAdd(&counts[dv.w], 1);
    } else {
        int b = e - N_EDGES;
        atomicAdd(&counts[b + 0], 1);
        atomicAdd(&counts[b + 1], 1);
        atomicAdd(&counts[b + 2], 1);
        atomicAdd(&counts[b + 3], 1);
    }
}

__global__ __launch_bounds__(256) void scan1_kernel(const int* __restrict__ counts,
                                                    int* __restrict__ localScan,
                                                    int* __restrict__ blockSums) {
    __shared__ int tmp[256];
    int t = threadIdx.x, i = blockIdx.x * 256 + t;
    int v = (i < N_NODES) ? counts[i] : 0;
    tmp[t] = v;
    __syncthreads();
    for (int d = 1; d < 256; d <<= 1) {
        int u = (t >= d) ? tmp[t - d] : 0;
        __syncthreads();
        tmp[t] += u;
        __syncthreads();
    }
    if (i < N_NODES) localScan[i] = tmp[t] - v;  // exclusive
    if (t == 255) blockSums[blockIdx.x] = tmp[t];
}

// merged scan2+scan3: every block redundantly scans the 196 block sums (cheap),
// then writes its 256 offsets.
__global__ __launch_bounds__(256) void scan23_kernel(const int* __restrict__ localScan,
                                                     const int* __restrict__ blockSums,
                                                     int* __restrict__ offs,
                                                     int* __restrict__ fill) {
    __shared__ int tmp[256];
    int t = threadIdx.x;
    int v = (t < SCAN_BLOCKS) ? blockSums[t] : 0;
    tmp[t] = v;
    __syncthreads();
    for (int d = 1; d < 256; d <<= 1) {
        int u = (t >= d) ? tmp[t - d] : 0;
        __syncthreads();
        tmp[t] += u;
        __syncthreads();
    }
    int b = blockIdx.x;
    int base = (b == 0) ? 0 : tmp[b - 1];
    int i = b * 256 + t;
    if (i < N_NODES) {
        int o = localScan[i] + base;
        offs[i] = o;
        fill[i] = o;
    }
    if (i == 0) offs[N_NODES] = E_TOT;
}

// deterministic ordering: sort each node's bucket by src id.
// one WAVE per node; <=64 elements sorted in-register via bitonic network.
__global__ __launch_bounds__(256) void sort_kernel(const int* __restrict__ offs,
                                                   int* __restrict__ bucket) {
    int w = (blockIdx.x * blockDim.x + threadIdx.x) >> 6;
    int l = threadIdx.x & 63;
    if (w >= N_NODES) return;
    int a = offs[w];
    int deg = offs[w + 1] - a;
    if (deg <= 1) return;
    if (deg <= 64) {
        int v = (l < deg) ? bucket[a + l] : 0x7fffffff;
#pragma unroll
        for (int k = 2; k <= 64; k <<= 1) {
#pragma unroll
            for (int j = k >> 1; j >= 1; j >>= 1) {
                int u = __shfl_xor(v, j, 64);
                bool up    = ((l & k) == 0);
                bool lower = ((l & j) == 0);
                int mn = min(v, u), mx = max(v, u);
                v = (up == lower) ? mn : mx;
            }
        }
        if (l < deg) bucket[a + l] = v;
    } else if (l == 0) {
        for (int i = a + 1; i < a + deg; i++) {
            int key = bucket[i];
            int j = i - 1;
            while (j >= a && bucket[j] > key) { bucket[j + 1] = bucket[j]; j--; }
            bucket[j + 1] = key;
        }
    }
}

// ---------------- fat kernel: gemm1 (blocks < GEMM_BLOCKS) || scatter (rest) ----
// gemm: block = 512 thr = 8 waves; wave w: head=w>>1, colhalf=w&1 (wave-uniform ->
// W reads are s_loads through the scalar cache). lane = node. Proven R7 design.
// scatter: dst-range partitioned (range = blockIdx&7 -> one XCD per range so the
// bucket region write-combines in that XCD's L2). Proven R7 design, 512-thr idx.
__global__ __launch_bounds__(512) void fat_kernel(const float* __restrict__ x,
                                                  const float* __restrict__ W1,
                                                  const float* __restrict__ asrc1,
                                                  const float* __restrict__ adst1,
                                                  __half* __restrict__ h1,
                                                  float* __restrict__ as1,
                                                  float* __restrict__ ad1,
                                                  const int* __restrict__ ei,
                                                  int* __restrict__ fill,
                                                  int* __restrict__ bucket) {
    __shared__ float xs[32 * 65];
    __shared__ float sredA[8 * 64];
    __shared__ float sredB[8 * 64];

    if (blockIdx.x >= GEMM_BLOCKS) {
        // ---- scatter part ----
        int r = blockIdx.x & (SCAT_RANGES - 1);        // XCD-stable range id
        int chunk = (blockIdx.x - GEMM_BLOCKS) >> 3;
        int e = (chunk * 512 + threadIdx.x) * 4;
        if (e >= E_TOT) return;
        int lo = r * RANGE_SIZE, hi = lo + RANGE_SIZE;
        int s0, s1, s2, s3, d0, d1, d2, d3;
        if (e < N_EDGES) {
            int4 sv = *(const int4*)(ei + e);
            int4 dv = *(const int4*)(ei + N_EDGES + e);
            s0 = sv.x; s1 = sv.y; s2 = sv.z; s3 = sv.w;
            d0 = dv.x; d1 = dv.y; d2 = dv.z; d3 = dv.w;
        } else {
            int b = e - N_EDGES;
            s0 = d0 = b; s1 = d1 = b + 1; s2 = d2 = b + 2; s3 = d3 = b + 3;
        }
        if (d0 >= lo && d0 < hi) { int p = atomicAdd(&fill[d0], 1); bucket[p] = s0; }
        if (d1 >= lo && d1 < hi) { int p = atomicAdd(&fill[d1], 1); bucket[p] = s1; }
        if (d2 >= lo && d2 < hi) { int p = atomicAdd(&fill[d2], 1); bucket[p] = s2; }
        if (d3 >= lo && d3 < hi) { int p = atomicAdd(&fill[d3], 1); bucket[p] = s3; }
        return;
    }

    // ---- gemm part ----
    const int tid  = threadIdx.x;
    const int lane = tid & 63;
    const int w    = tid >> 6;
    const int head = __builtin_amdgcn_readfirstlane(w >> 1);
    const int ch   = __builtin_amdgcn_readfirstlane(w & 1);
    const int base = blockIdx.x * GBLK;
    const int node = base + lane;

    const float* __restrict__ wh = W1 + head * 32 + ch * 16;

    float acc[16];
#pragma unroll
    for (int j = 0; j < 16; j++) acc[j] = 0.f;

    for (int kt = 0; kt < 4; kt++) {
        __syncthreads();
        {
            int row = tid >> 3, c4 = tid & 7;
            int n2 = base + row;
            float4 v = make_float4(0.f, 0.f, 0.f, 0.f);
            if (n2 < N_NODES)
                v = *(const float4*)(x + (size_t)n2 * 128 + kt * 32 + c4 * 4);
            xs[(c4 * 4 + 0) * 65 + row] = v.x;
            xs[(c4 * 4 + 1) * 65 + row] = v.y;
            xs[(c4 * 4 + 2) * 65 + row] = v.z;
            xs[(c4 * 4 + 3) * 65 + row] = v.w;
        }
        __syncthreads();

#pragma unroll 4
        for (int kk = 0; kk < 32; kk++) {
            float xv = xs[kk * 65 + lane];
            const float* __restrict__ wr = wh + (size_t)(kt * 32 + kk) * 128;
#pragma unroll
            for (int j = 0; j < 16; j++)
                acc[j] += xv * wr[j];
        }
    }

    if (node < N_NODES) {
        __half2 hp[8];
#pragma unroll
        for (int j = 0; j < 8; j++)
            hp[j] = __floats2half2_rn(acc[2 * j], acc[2 * j + 1]);
        float4* dst = (float4*)(h1 + (size_t)node * 128 + head * 32 + ch * 16);
        dst[0] = ((float4*)hp)[0];
        dst[1] = ((float4*)hp)[1];
    }

    float sa = 0.f, da = 0.f;
#pragma unroll
    for (int j = 0; j < 16; j++) {
        float v = acc[j];
        sa += v * asrc1[head * 32 + ch * 16 + j];
        da += v * adst1[head * 32 + ch * 16 + j];
    }
    sredA[w * 64 + lane] = sa;
    sredB[w * 64 + lane] = da;
    __syncthreads();
    if (tid < 256) {
        int hh = tid >> 6;
        int nd = base + lane;
        if (nd < N_NODES) {
            as1[nd * 4 + hh] = sredA[(hh * 2) * 64 + lane] + sredA[(hh * 2 + 1) * 64 + lane];
            ad1[nd * 4 + hh] = sredB[(hh * 2) * 64 + lane] + sredB[(hh * 2 + 1) * 64 + lane];
        }
    }
}

// ---------------- layer 1 aggregation (+bias, ELU, layer-2 projection) ----------------
// wave per node. lane = (edge-subset l>>4, channel-group l&15 -> 8 channels).
// One dwordx4 h1 load covers 4 src rows per iteration; exp/leaky amortize over
// 4 edges. Channel partials reduced across edge-subsets via shfl_xor(16,32).
__global__ __launch_bounds__(256) void agg1_kernel(const __half* __restrict__ h1,
                                                   const float* __restrict__ as1,
                                                   const float* __restrict__ ad1,
                                                   const int* __restrict__ offs,
                                                   const int* __restrict__ bucket,
                                                   const float* __restrict__ b1,
                                                   const float* __restrict__ W2,
                                                   float* __restrict__ h2s) {
    int w = threadIdx.x >> 6, l = threadIdx.x & 63;
    int node = blockIdx.x * 4 + w;
    if (node >= N_NODES) return;
    int sub = l & 15;            // channels 8*sub .. 8*sub+7
    int ep  = l >> 4;            // edge subset 0..3
    int head = sub >> 2;
    float adh = ad1[node * 4 + head];
    int a = offs[node];
    int deg = offs[node + 1] - a;

    float c[8];
#pragma unroll
    for (int k = 0; k < 8; k++) c[k] = 0.f;
    float sx = 0.f;

    for (int i = 0; i < deg; i += 4) {
        int idx = i + ep;
        bool valid = idx < deg;
        int s = bucket[a + (valid ? idx : 0)];
        float e = as1[s * 4 + head] + adh;
        e = fmaxf(e, 0.2f * e);                     // leaky_relu, slope<1
        float ex = valid ? __expf(e) : 0.f;
        float4 hv = *(const float4*)(h1 + (size_t)s * 128 + sub * 8);
        const __half2* hh = (const __half2*)&hv;
        float2 f0 = __half22float2(hh[0]);
        float2 f1 = __half22float2(hh[1]);
        float2 f2 = __half22float2(hh[2]);
        float2 f3 = __half22float2(hh[3]);
        sx += ex;
        c[0] += ex * f0.x; c[1] += ex * f0.y;
        c[2] += ex * f1.x; c[3] += ex * f1.y;
        c[4] += ex * f2.x; c[5] += ex * f2.y;
        c[6] += ex * f3.x; c[7] += ex * f3.y;
    }

    // reduce over edge subsets (lane bits 4,5)
#pragma unroll
    for (int k = 0; k < 8; k++) {
        c[k] += __shfl_xor(c[k], 16, 64);
        c[k] += __shfl_xor(c[k], 32, 64);
    }
    sx += __shfl_xor(sx, 16, 64);
    sx += __shfl_xor(sx, 32, 64);

    float r = 1.f / (sx + 1e-16f);
    float4 blo = ((const float4*)b1)[sub * 2];
    float4 bhi = ((const float4*)b1)[sub * 2 + 1];
    float4 wlo = ((const float4*)W2)[sub * 2];
    float4 whi = ((const float4*)W2)[sub * 2 + 1];
    float ob[8] = {blo.x, blo.y, blo.z, blo.w, bhi.x, bhi.y, bhi.z, bhi.w};
    float ow[8] = {wlo.x, wlo.y, wlo.z, wlo.w, whi.x, whi.y, whi.z, whi.w};
    float p = 0.f;
#pragma unroll
    for (int k = 0; k < 8; k++) {
        float o = c[k] * r + ob[k];
        float el = (o > 0.f) ? o : (__expf(o) - 1.f);  // ELU
        p += el * ow[k];
    }
    // reduce over channel groups (lane bits 0..3)
    p += __shfl_xor(p, 1, 64);
    p += __shfl_xor(p, 2, 64);
    p += __shfl_xor(p, 4, 64);
    p += __shfl_xor(p, 8, 64);
    if (l == 0) h2s[node] = p;
}

// ---------------- layer 2 aggregation ----------------
__global__ __launch_bounds__(256) void agg2_kernel(const float* __restrict__ h2s,
                                                   const int* __restrict__ offs,
                                                   const int* __restrict__ bucket,
                                                   const float* __restrict__ asrc2,
                                                   const float* __restrict__ adst2,
                                                   const float* __restrict__ b2,
                                                   float* __restrict__ out) {
    int w = threadIdx.x >> 6, l = threadIdx.x & 63;
    int node = blockIdx.x * 4 + w;
    if (node >= N_NODES) return;
    float asc = asrc2[0], adc = adst2[0], bias = b2[0];
    float adn = h2s[node] * adc;
    int a = offs[node], b = offs[node + 1];
    float sx = 0.f, sw = 0.f;
    for (int i = a + l; i < b; i += 64) {
        float hs = h2s[bucket[i]];
        float e = hs * asc + adn;
        e = fmaxf(e, 0.2f * e);
        float ex = __expf(e);
        sx += ex;
        sw += ex * hs;
    }
#pragma unroll
    for (int o = 32; o > 0; o >>= 1) {
        sx += __shfl_xor(sx, o, 64);
        sw += __shfl_xor(sw, o, 64);
    }
    if (l == 0) out[node] = sw / (sx + 1e-16f) + bias;
}

// ---------------- launch ----------------

extern "C" void kernel_launch(void* const* d_in, const int* in_sizes, int n_in,
                              void* d_out, int out_size, void* d_ws, size_t ws_size,
                              hipStream_t stream) {
    const float* x     = (const float*)d_in[0];
    const int*   ei    = (const int*)d_in[1];
    const float* W1    = (const float*)d_in[2];
    const float* asrc1 = (const float*)d_in[3];
    const float* adst1 = (const float*)d_in[4];
    const float* b1    = (const float*)d_in[5];
    const float* W2    = (const float*)d_in[6];
    const float* asrc2 = (const float*)d_in[7];
    const float* adst2 = (const float*)d_in[8];
    const float* b2    = (const float*)d_in[9];
    float* out = (float*)d_out;

    char* ws = (char*)d_ws;
    size_t o = 0;
    auto alloc = [&](size_t bytes) -> void* {
        void* p = ws + o;
        o += (bytes + 255) & ~(size_t)255;
        return p;
    };
    int* counts  = (int*)alloc((size_t)N_NODES * 4);
    int* offs    = (int*)alloc((size_t)(N_NODES + 1) * 4);
    int* fill    = (int*)alloc((size_t)N_NODES * 4);
    int* bucket  = (int*)alloc((size_t)E_TOT * 4);
    __half* h1   = (__half*)alloc((size_t)N_NODES * 128 * 2);
    float* as1   = (float*)alloc((size_t)N_NODES * 4 * 4);
    float* ad1   = (float*)alloc((size_t)N_NODES * 4 * 4);
    float* h2s   = (float*)alloc((size_t)N_NODES * 4);
    int* localScan = (int*)alloc((size_t)N_NODES * 4);
    int* blockSums = (int*)alloc((size_t)SCAN_BLOCKS * 4);

    hipMemsetAsync(counts, 0, (size_t)N_NODES * 4, stream);

    hist_kernel<<<(E_TOT / 4 + 255) / 256, 256, 0, stream>>>(ei, counts);
    scan1_kernel<<<SCAN_BLOCKS, 256, 0, stream>>>(counts, localScan, blockSums);
    scan23_kernel<<<SCAN_BLOCKS, 256, 0, stream>>>(localScan, blockSums, offs, fill);

    fat_kernel<<<GEMM_BLOCKS + SCAT_BLOCKS, 512, 0, stream>>>(
        x, W1, asrc1, adst1, h1, as1, ad1, ei, fill, bucket);

    sort_kernel<<<(N_NODES * 64 + 255) / 256, 256, 0, stream>>>(offs, bucket);

    agg1_kernel<<<(N_NODES + 3) / 4, 256, 0, stream>>>(
        h1, as1, ad1, offs, bucket, b1, W2, h2s);

    agg2_kernel<<<(N_NODES + 3) / 4, 256, 0, stream>>>(
        h2s, offs, bucket, asrc2, adst2, b2, out);
}